// Round 1
// baseline (138.382 us; speedup 1.0000x reference)
//
#include <hip/hip_runtime.h>
#include <math.h>

#define BLOCK 256

__global__ __launch_bounds__(BLOCK) void traj_cost_kernel(
    const float* __restrict__ pos,    // (N, 3)
    const float* __restrict__ rot,    // (N, 3, 3)
    const float* __restrict__ gpos,   // (H, 3)
    const float* __restrict__ grot,   // (H, 3, 3)
    float* __restrict__ out,          // cost[N] | rot_err_norm[N] | goal_dist[N]
    long long N, int H)
{
    __shared__ float s_rot[BLOCK * 9];   // 9216 B
    __shared__ float s_pos[BLOCK * 3];   // 3072 B

    const int tid = threadIdx.x;
    const long long base = (long long)blockIdx.x * BLOCK;

    if (base + BLOCK <= N) {
        // Fast path: stage 256 poses. rot chunk = 2304 floats = 576 float4,
        // pos chunk = 768 floats = 192 float4. Block base byte offsets are
        // 9216/3072 — 16B aligned. Fully coalesced.
        const float4* r4 = (const float4*)(rot + base * 9);
        float4* s4 = (float4*)s_rot;
        s4[tid]        = r4[tid];
        s4[tid + 256]  = r4[tid + 256];
        if (tid < 64) s4[tid + 512] = r4[tid + 512];
        const float4* p4 = (const float4*)(pos + base * 3);
        float4* sp4 = (float4*)s_pos;
        if (tid < 192) sp4[tid] = p4[tid];
    } else {
        const int nel = (int)(N - base);
        for (int k = tid; k < nel * 9; k += BLOCK) s_rot[k] = rot[base * 9 + k];
        for (int k = tid; k < nel * 3; k += BLOCK) s_pos[k] = pos[base * 3 + k];
    }
    __syncthreads();

    const long long idx = base + tid;
    if (idx >= N) return;
    const int h = (int)(idx % (long long)H);

    // LDS reads: word-stride 9 / 3 across lanes -> every bank hit exactly
    // twice per wave64 = free 2-way aliasing on gfx950.
    float R[9], P[3], G[9], GP[3];
    #pragma unroll
    for (int c = 0; c < 9; ++c) R[c] = s_rot[tid * 9 + c];
    #pragma unroll
    for (int c = 0; c < 3; ++c) P[c] = s_pos[tid * 3 + c];
    #pragma unroll
    for (int c = 0; c < 9; ++c) G[c] = grot[h * 9 + c];   // 12KB array: L1 hit
    #pragma unroll
    for (int c = 0; c < 3; ++c) GP[c] = gpos[h * 3 + c];

    // t[i] = ee_t_g[i] = -sum_j G[j,i]*GP[j] + sum_j R[j,i]*P[j]
    float t[3];
    #pragma unroll
    for (int i = 0; i < 3; ++i) {
        float a = 0.f;
        #pragma unroll
        for (int j = 0; j < 3; ++j)
            a += R[j * 3 + i] * P[j] - G[j * 3 + i] * GP[j];
        t[i] = a;
    }
    // pos_weight == (1,1,1)
    float pos_err = t[0] * t[0] + t[1] * t[1] + t[2] * t[2];
    float goal_dist = pos_err > 0.f ? sqrtf(pos_err) : 0.f;

    // ee_R_g[i,j] = sum_k G[k,i] * R[k,j]; d = I - ee_R_g
    float rn[3];
    #pragma unroll
    for (int i = 0; i < 3; ++i) {
        float q = 0.f;
        #pragma unroll
        for (int j = 0; j < 3; ++j) {
            float m = G[0 * 3 + i] * R[0 * 3 + j]
                    + G[1 * 3 + i] * R[1 * 3 + j]
                    + G[2 * 3 + i] * R[2 * 3 + j];
            float d = (i == j ? 1.f : 0.f) - m;
            q += d * d;
        }
        rn[i] = q > 0.f ? sqrtf(q) : 0.f;   // row_norm, rot_weight == 1
    }
    float s  = rn[0] + rn[1] + rn[2];
    float q2 = rn[0] * rn[0] + rn[1] * rn[1] + rn[2] * rn[2];
    float rot_err_norm = q2 > 0.f ? sqrtf(q2) : 0.f;

    // rot_err = s^2, hinged on goal_dist <= 100; convergence thresholds are 0
    // (no-op on non-negative values). cost = safe_sqrt(rot_err) + safe_sqrt(pos_err).
    float rot_err = s * s;
    if (goal_dist > 100.0f) rot_err = 0.f;
    float cost = (rot_err > 0.f ? sqrtf(rot_err) : 0.f) + goal_dist;

    out[idx]         = cost;
    out[N + idx]     = rot_err_norm;
    out[2 * N + idx] = goal_dist;
}

extern "C" void kernel_launch(void* const* d_in, const int* in_sizes, int n_in,
                              void* d_out, int out_size, void* d_ws, size_t ws_size,
                              hipStream_t stream) {
    const float* pos  = (const float*)d_in[0];
    const float* rot  = (const float*)d_in[1];
    const float* gpos = (const float*)d_in[2];
    const float* grot = (const float*)d_in[3];
    float* out = (float*)d_out;

    const long long N = (long long)in_sizes[0] / 3;   // B*H poses
    const int H = in_sizes[2] / 3;

    const int blocks = (int)((N + BLOCK - 1) / BLOCK);
    traj_cost_kernel<<<blocks, BLOCK, 0, stream>>>(pos, rot, gpos, grot, out, N, H);
}